// Round 8
// baseline (154.627 us; speedup 1.0000x reference)
//
#include <hip/hip_runtime.h>
#include <math.h>

// Problem constants (from reference setup_inputs)
#define BB 32
#define CC 512
#define CR 32     // C/r

typedef float floatx4 __attribute__((ext_vector_type(4)));

__device__ __forceinline__ float wave_sum64(float v) {
    #pragma unroll
    for (int off = 32; off > 0; off >>= 1)
        v += __shfl_xor(v, off, 64);
    return v;
}

// --- Pass 1 (fused gauss): sq[b][c] = sum_{h,w} x[b,c,h,w]*kx[b,h]*ky[b,w]
// grid = (C/4, B), block = 256 (4 waves); wave wv handles channel bx*4+wv.
__global__ void k_squeeze(const float* __restrict__ x,
                          const float* __restrict__ mu,
                          const float* __restrict__ log_sigma,
                          float* __restrict__ sq) {
    __shared__ float s_kx[64];
    __shared__ float s_ky[64];
    int b = blockIdx.y;
    int tid = threadIdx.x;

    if (tid < 64) {
        float sigma = expf(log_sigma[0]);
        float inv2s = 1.0f / (2.0f * sigma);
        float g = (float)tid / 63.0f;       // linspace(0,1,64)
        float dh = g - mu[b * 2 + 0];       // grid_x varies along h -> mu[:,0]
        float dw = g - mu[b * 2 + 1];       // grid_y varies along w -> mu[:,1]
        float vx = expf(-dh * dh * inv2s);
        float vy = expf(-dw * dw * inv2s);
        float sx = wave_sum64(vx);
        float sy = wave_sum64(vy);
        s_kx[tid] = vx / sx;
        s_ky[tid] = vy / sy;
    }
    __syncthreads();

    int wv = tid >> 6;
    int lane = tid & 63;
    int c = blockIdx.x * 4 + wv;
    const floatx4* xp = (const floatx4*)(x + ((size_t)(b * CC + c)) * 4096);
    int col = lane & 15;           // which float4 within a row (w0 = col*4)
    int hbase = lane >> 4;         // 0..3
    float a0 = 0.f, a1 = 0.f, a2 = 0.f, a3 = 0.f;
    #pragma unroll
    for (int it = 0; it < 16; ++it) {
        int h = hbase + it * 4;    // 64 lanes cover 4 full rows (1 KiB contiguous)
        floatx4 v = __builtin_nontemporal_load(xp + h * 16 + col);
        float kh = s_kx[h];
        a0 += v.x * kh; a1 += v.y * kh; a2 += v.z * kh; a3 += v.w * kh;
    }
    int w0 = col * 4;
    float partial = a0 * s_ky[w0] + a1 * s_ky[w0 + 1] + a2 * s_ky[w0 + 2] + a3 * s_ky[w0 + 3];
    float s = wave_sum64(partial);
    if (lane == 0) sq[b * CC + c] = s;
}

// --- Pass 2 (fused MLP + scale): each block recomputes the tiny MLP for its
// batch, derives sigmoid weights for its 8 channels, streams out = x * w.
// grid = (64, B), block = 256.
__global__ void k_scale(const float* __restrict__ x,
                        const float* __restrict__ sq,
                        const float* __restrict__ w1,   // (CR, C)
                        const float* __restrict__ w2,   // (C, CR)
                        float* __restrict__ out) {
    __shared__ float s_sq[CC];
    __shared__ float s_hid[CR];
    __shared__ float s_w[8];
    int b = blockIdx.y;
    int c0 = blockIdx.x * 8;
    int tid = threadIdx.x;

    for (int i = tid; i < CC; i += 256) s_sq[i] = sq[b * CC + i];
    __syncthreads();
    {   // hid[j] = relu(w1[j,:] . sq) : 32 j x 8 segments of 64 cols
        int j = tid >> 3;
        int seg = tid & 7;
        float a = 0.f;
        const float* w1r = w1 + j * CC + seg * 64;
        const float* sqr = s_sq + seg * 64;
        #pragma unroll 8
        for (int c = 0; c < 64; ++c) a += sqr[c] * w1r[c];
        a += __shfl_xor(a, 4, 64);
        a += __shfl_xor(a, 2, 64);
        a += __shfl_xor(a, 1, 64);
        if (seg == 0) s_hid[j] = fmaxf(a, 0.0f);
    }
    __syncthreads();
    if (tid < 8) {
        const float* w2r = w2 + (size_t)(c0 + tid) * CR;
        float a = 0.f;
        #pragma unroll
        for (int jj = 0; jj < CR; ++jj) a += s_hid[jj] * w2r[jj];
        s_w[tid] = 1.0f / (1.0f + expf(-a));
    }
    __syncthreads();

    // stream 8 channels x 4096 floats = 8192 float4; 256 threads -> 32 iters
    const size_t base = ((size_t)(b * CC + c0)) * 4096;
    const floatx4* xp = (const floatx4*)(x + base);
    floatx4* op = (floatx4*)(out + base);
    #pragma unroll 8
    for (int it = 0; it < 32; ++it) {
        int idx = it * 256 + tid;          // 1024 float4 per channel
        float s = s_w[idx >> 10];
        floatx4 v = __builtin_nontemporal_load(xp + idx);
        __builtin_nontemporal_store(v * s, op + idx);
    }
}

extern "C" void kernel_launch(void* const* d_in, const int* in_sizes, int n_in,
                              void* d_out, int out_size, void* d_ws, size_t ws_size,
                              hipStream_t stream) {
    const float* x  = (const float*)d_in[0];
    const float* mu = (const float*)d_in[1];
    const float* ls = (const float*)d_in[2];
    const float* w1 = (const float*)d_in[3];
    const float* w2 = (const float*)d_in[4];
    float* out = (float*)d_out;
    float* sq = (float*)d_ws;       // B*C = 16384 floats

    k_squeeze<<<dim3(CC / 4, BB), 256, 0, stream>>>(x, mu, ls, sq);
    k_scale<<<dim3(64, BB), 256, 0, stream>>>(x, sq, w1, w2, out);
}

// Round 9
// 133.593 us; speedup vs baseline: 1.1575x; 1.1575x over previous
//
#include <hip/hip_runtime.h>
#include <math.h>

// Problem constants (from reference setup_inputs)
#define BB 32
#define CC 512
#define HH 64
#define WW 64
#define RR 16
#define CR (CC / RR)   // 32

typedef float floatx4 __attribute__((ext_vector_type(4)));

__device__ __forceinline__ float wave_sum64(float v) {
    #pragma unroll
    for (int off = 32; off > 0; off >>= 1)
        v += __shfl_xor(v, off, 64);
    return v;
}

// --- Kernel B (fused gauss): squeezed[b][c] = sum_{h,w} x[b,c,h,w]*kx[b,h]*ky[b,w]
// grid = (C/4, B), block = 256 (4 waves); wave wv handles channel c = bx*4+wv.
// Plain (L2-allocating) loads: measured faster than nt-loads for this stream.
__global__ void k_squeeze(const float* __restrict__ x,
                          const float* __restrict__ mu,
                          const float* __restrict__ log_sigma,
                          float* __restrict__ sq) {
    __shared__ float s_kx[64];
    __shared__ float s_ky[64];
    int b = blockIdx.y;
    int tid = threadIdx.x;

    if (tid < 64) {
        float sigma = expf(log_sigma[0]);
        float inv2s = 1.0f / (2.0f * sigma);
        float g = (float)tid / 63.0f;       // linspace(0,1,64)
        float dh = g - mu[b * 2 + 0];       // grid_x varies along h -> mu[:,0]
        float dw = g - mu[b * 2 + 1];       // grid_y varies along w -> mu[:,1]
        float vx = expf(-dh * dh * inv2s);
        float vy = expf(-dw * dw * inv2s);
        float sx = wave_sum64(vx);
        float sy = wave_sum64(vy);
        s_kx[tid] = vx / sx;
        s_ky[tid] = vy / sy;
    }
    __syncthreads();

    int wv = tid >> 6;
    int lane = tid & 63;
    int c = blockIdx.x * 4 + wv;
    const floatx4* xp = (const floatx4*)(x + ((size_t)(b * CC + c)) * (HH * WW));
    int col = lane & 15;           // which float4 within a row (w0 = col*4)
    int hbase = lane >> 4;         // 0..3
    float a0 = 0.f, a1 = 0.f, a2 = 0.f, a3 = 0.f;
    #pragma unroll
    for (int it = 0; it < 16; ++it) {
        int h = hbase + it * 4;    // 64 lanes cover 4 full rows (1 KiB contiguous)
        floatx4 v = xp[h * 16 + col];
        float kh = s_kx[h];
        a0 += v.x * kh; a1 += v.y * kh; a2 += v.z * kh; a3 += v.w * kh;
    }
    int w0 = col * 4;
    float partial = a0 * s_ky[w0] + a1 * s_ky[w0 + 1] + a2 * s_ky[w0 + 2] + a3 * s_ky[w0 + 3];
    float s = wave_sum64(partial);
    if (lane == 0) sq[b * CC + c] = s;
}

// --- Kernel C: weights[b][c] = sigmoid( relu(sq @ w1^T) @ w2^T ) ---
// grid = B blocks, block = 256 (runs once per batch; keeps w1 traffic tiny)
__global__ void k_mlp(const float* __restrict__ sq,
                      const float* __restrict__ w1,   // (CR, C)
                      const float* __restrict__ w2,   // (C, CR)
                      float* __restrict__ weights) {
    __shared__ float s_sq[CC];
    __shared__ float s_hid[CR];
    int b = blockIdx.x;
    int tid = threadIdx.x;
    for (int c = tid; c < CC; c += 256) s_sq[c] = sq[b * CC + c];
    __syncthreads();
    // hid[j]: 256 threads = 32 j-values x 8 segments of 64 columns
    int j = tid >> 3;
    int seg = tid & 7;
    float acc = 0.f;
    const float* w1r = w1 + j * CC + seg * 64;
    const float* sqr = s_sq + seg * 64;
    #pragma unroll 8
    for (int c = 0; c < 64; ++c) acc += sqr[c] * w1r[c];
    acc += __shfl_xor(acc, 4, 64);
    acc += __shfl_xor(acc, 2, 64);
    acc += __shfl_xor(acc, 1, 64);
    if (seg == 0) s_hid[j] = fmaxf(acc, 0.0f);
    __syncthreads();
    for (int c = tid; c < CC; c += 256) {
        float a = 0.f;
        const float* w2r = w2 + c * CR;
        #pragma unroll
        for (int jj = 0; jj < CR; ++jj) a += s_hid[jj] * w2r[jj];
        weights[b * CC + c] = 1.0f / (1.0f + expf(-a));
    }
}

// --- Kernel D: out = x * weights[b,c] ---
// Reverse grid-stride sweep + non-temporal stores (measured best).
__global__ void k_scale(const float* __restrict__ x,
                        const float* __restrict__ wt,
                        float* __restrict__ out, long n4) {
    long gid = (long)blockIdx.x * blockDim.x + threadIdx.x;
    long stride = (long)gridDim.x * blockDim.x;
    long niter = n4 / stride;                  // exact: 16777216 / 524288 = 32
    for (long j = niter; j-- > 0; ) {
        long i = j * stride + gid;
        floatx4 v = ((const floatx4*)x)[i];
        float s = wt[i >> 10];                 // 1024 float4 per (b,c) channel
        floatx4 o = v * s;
        __builtin_nontemporal_store(o, ((floatx4*)out) + i);
    }
}

extern "C" void kernel_launch(void* const* d_in, const int* in_sizes, int n_in,
                              void* d_out, int out_size, void* d_ws, size_t ws_size,
                              hipStream_t stream) {
    const float* x  = (const float*)d_in[0];
    const float* mu = (const float*)d_in[1];
    const float* ls = (const float*)d_in[2];
    const float* w1 = (const float*)d_in[3];
    const float* w2 = (const float*)d_in[4];
    float* out = (float*)d_out;

    float* ws = (float*)d_ws;
    float* sq = ws;                 // B*C = 16384 floats
    float* wt = ws + 16384;         // B*C = 16384 floats

    k_squeeze<<<dim3(CC / 4, BB), 256, 0, stream>>>(x, mu, ls, sq);
    k_mlp<<<BB, 256, 0, stream>>>(sq, w1, w2, wt);
    k_scale<<<2048, 256, 0, stream>>>(x, wt, out, (long)BB * CC * HH * WW / 4);
}